// Round 1
// baseline (31268.106 us; speedup 1.0000x reference)
//
#include <hip/hip_runtime.h>

static constexpr int B = 2048;
static constexpr int S = 128;
static constexpr int D = 128;
static constexpr int H = 256;

__device__ __forceinline__ float fsig(float x)  { return 1.0f / (1.0f + __expf(-x)); }
__device__ __forceinline__ float ftanh(float x) { return 1.0f - 2.0f / (__expf(2.0f * x) + 1.0f); }

// One LSTM layer step over the full batch.
// z[b, g*H+j] = sum_k xin[b,k]*Wih[g*H+j,k] + sum_k hprev[b,k]*Whh[g*H+j,k] + bih[g*H+j] + bhh[g*H+j]
// Gates (PyTorch order i,f,g,o) -> c,h update, fused.
// Tile: BM=64 batch rows x BN=32 hidden cols (=> 128 z columns), 256 threads.
// Each thread: 8 batch rows x 1 hidden col x 4 gates = 32 accumulators.
__global__ __launch_bounds__(256)
void lstm_step(const float* __restrict__ xin, int KX, int ldx,
               const float* __restrict__ hprev,
               const float* __restrict__ Wih,
               const float* __restrict__ Whh,
               const float* __restrict__ bih,
               const float* __restrict__ bhh,
               const float* __restrict__ cprev,
               float* __restrict__ hout,
               float* __restrict__ cout)
{
    constexpr int KT = 32, LDP = KT + 4;     // +4 pad keeps 16B alignment, breaks bank aliasing
    __shared__ float As[64 * LDP];           // 64 batch rows x 32 k
    __shared__ float Ws[128 * LDP];          // 128 z-rows (4 gates x 32 cols) x 32 k

    const int tid = threadIdx.x;
    const int tx = tid & 31;                 // hidden col within tile
    const int ty = tid >> 5;                 // batch subgroup 0..7
    const int j0 = blockIdx.x * 32;
    const int b0 = blockIdx.y * 64;

    float acc[8][4];
    #pragma unroll
    for (int r = 0; r < 8; ++r)
        #pragma unroll
        for (int g = 0; g < 4; ++g) acc[r][g] = 0.0f;

    #pragma unroll
    for (int pass = 0; pass < 2; ++pass) {
        const float* Ag  = pass ? hprev : xin;
        const float* Wg  = pass ? Whh   : Wih;
        const int    K   = pass ? H     : KX;
        const int    lda = pass ? H     : ldx;
        const int    ldw = pass ? H     : KX;
        for (int k0 = 0; k0 < K; k0 += KT) {
            // stage A tile: 64 rows x 32 k = 512 float4 -> 2 per thread
            #pragma unroll
            for (int i = 0; i < 2; ++i) {
                int idx = tid + i * 256;
                int row = idx >> 3;
                int kq  = idx & 7;
                float4 v = *(const float4*)(Ag + (size_t)(b0 + row) * lda + k0 + kq * 4);
                *(float4*)(&As[row * LDP + kq * 4]) = v;
            }
            // stage W tile: 128 z-rows x 32 k = 1024 float4 -> 4 per thread
            #pragma unroll
            for (int i = 0; i < 4; ++i) {
                int idx = tid + i * 256;
                int zr  = idx >> 3;          // 0..127
                int kq  = idx & 7;
                int g   = zr >> 5;
                int jj  = zr & 31;
                float4 v = *(const float4*)(Wg + (size_t)(g * H + j0 + jj) * ldw + k0 + kq * 4);
                *(float4*)(&Ws[zr * LDP + kq * 4]) = v;
            }
            __syncthreads();
            #pragma unroll
            for (int kk = 0; kk < KT; kk += 4) {
                float4 a4[8];
                float4 w4[4];
                #pragma unroll
                for (int r = 0; r < 8; ++r)
                    a4[r] = *(const float4*)(&As[(ty + r * 8) * LDP + kk]);
                #pragma unroll
                for (int g = 0; g < 4; ++g)
                    w4[g] = *(const float4*)(&Ws[(g * 32 + tx) * LDP + kk]);
                #pragma unroll
                for (int r = 0; r < 8; ++r)
                    #pragma unroll
                    for (int g = 0; g < 4; ++g) {
                        acc[r][g] += a4[r].x * w4[g].x;
                        acc[r][g] += a4[r].y * w4[g].y;
                        acc[r][g] += a4[r].z * w4[g].z;
                        acc[r][g] += a4[r].w * w4[g].w;
                    }
            }
            __syncthreads();
        }
    }

    const int j = j0 + tx;
    const float b_i = bih[0 * H + j] + bhh[0 * H + j];
    const float b_f = bih[1 * H + j] + bhh[1 * H + j];
    const float b_g = bih[2 * H + j] + bhh[2 * H + j];
    const float b_o = bih[3 * H + j] + bhh[3 * H + j];
    #pragma unroll
    for (int r = 0; r < 8; ++r) {
        const size_t bi = (size_t)(b0 + ty + r * 8) * H + j;
        float ig = fsig (acc[r][0] + b_i);
        float fg = fsig (acc[r][1] + b_f);
        float gg = ftanh(acc[r][2] + b_g);
        float og = fsig (acc[r][3] + b_o);
        float c  = fg * cprev[bi] + ig * gg;
        float h  = og * ftanh(c);
        cout[bi] = c;
        hout[bi] = h;
    }
}

// out[:, t, :] = h2 @ Wout^T + bout   (M=2048, N=128, K=256)
__global__ __launch_bounds__(256)
void proj_step(const float* __restrict__ h2,
               const float* __restrict__ Wout,
               const float* __restrict__ bout,
               float* __restrict__ out, int t)
{
    constexpr int KT = 32, LDP = KT + 4;
    __shared__ float As[64 * LDP];
    __shared__ float Bs[32 * LDP];
    const int tid = threadIdx.x;
    const int tx = tid & 31;
    const int ty = tid >> 5;
    const int n0 = blockIdx.x * 32;
    const int b0 = blockIdx.y * 64;

    float acc[8];
    #pragma unroll
    for (int r = 0; r < 8; ++r) acc[r] = 0.0f;

    for (int k0 = 0; k0 < H; k0 += KT) {
        #pragma unroll
        for (int i = 0; i < 2; ++i) {
            int idx = tid + i * 256;
            int row = idx >> 3, kq = idx & 7;
            *(float4*)(&As[row * LDP + kq * 4]) =
                *(const float4*)(h2 + (size_t)(b0 + row) * H + k0 + kq * 4);
        }
        {
            int row = tid >> 3, kq = tid & 7;   // 32 rows x 8 quads = 256
            *(float4*)(&Bs[row * LDP + kq * 4]) =
                *(const float4*)(Wout + (size_t)(n0 + row) * H + k0 + kq * 4);
        }
        __syncthreads();
        #pragma unroll
        for (int kk = 0; kk < KT; kk += 4) {
            float4 w = *(const float4*)(&Bs[tx * LDP + kk]);
            #pragma unroll
            for (int r = 0; r < 8; ++r) {
                float4 a = *(const float4*)(&As[(ty + r * 8) * LDP + kk]);
                acc[r] += a.x * w.x + a.y * w.y + a.z * w.z + a.w * w.w;
            }
        }
        __syncthreads();
    }
    const float bo = bout[n0 + tx];
    #pragma unroll
    for (int r = 0; r < 8; ++r) {
        int b = b0 + ty + r * 8;
        out[((size_t)b * S + t) * D + n0 + tx] = acc[r] + bo;
    }
}

extern "C" void kernel_launch(void* const* d_in, const int* in_sizes, int n_in,
                              void* d_out, int out_size, void* d_ws, size_t ws_size,
                              hipStream_t stream)
{
    const float* x     = (const float*)d_in[0];
    const float* eWih0 = (const float*)d_in[1];
    const float* eWhh0 = (const float*)d_in[2];
    const float* ebih0 = (const float*)d_in[3];
    const float* ebhh0 = (const float*)d_in[4];
    const float* eWih1 = (const float*)d_in[5];
    const float* eWhh1 = (const float*)d_in[6];
    const float* ebih1 = (const float*)d_in[7];
    const float* ebhh1 = (const float*)d_in[8];
    const float* dWih0 = (const float*)d_in[9];
    const float* dWhh0 = (const float*)d_in[10];
    const float* dbih0 = (const float*)d_in[11];
    const float* dbhh0 = (const float*)d_in[12];
    const float* dWih1 = (const float*)d_in[13];
    const float* dWhh1 = (const float*)d_in[14];
    const float* dbih1 = (const float*)d_in[15];
    const float* dbhh1 = (const float*)d_in[16];
    const float* Wout  = (const float*)d_in[17];
    const float* bout  = (const float*)d_in[18];
    float* out = (float*)d_out;

    float* ws = (float*)d_ws;
    const size_t BH = (size_t)B * H;
    float* eh1[2] = { ws + 0 * BH, ws + 1 * BH };
    float* ec1    =   ws + 2 * BH;
    float* eh2[2] = { ws + 3 * BH, ws + 4 * BH };
    float* ec2    =   ws + 5 * BH;
    float* dh1[2] = { ws + 6 * BH, ws + 7 * BH };
    float* dc1    =   ws + 8 * BH;
    float* dh2[2] = { ws + 9 * BH, ws + 10 * BH };
    float* dc2    =   ws + 11 * BH;

    // zero all h/c state each call (deterministic; graph-capture-safe memset node)
    hipMemsetAsync(d_ws, 0, 12 * BH * sizeof(float), stream);

    dim3 blk(256);
    dim3 grdL(H / 32, B / 64);   // (8, 32) = 256 blocks
    dim3 grdP(D / 32, B / 64);   // (4, 32) = 128 blocks

    // ---- encoder: 2-layer LSTM over S steps ----
    for (int t = 0; t < S; ++t) {
        int pr = t & 1, pw = (t + 1) & 1;
        lstm_step<<<grdL, blk, 0, stream>>>(x + (size_t)t * D, D, S * D,
            eh1[pr], eWih0, eWhh0, ebih0, ebhh0, ec1, eh1[pw], ec1);
        lstm_step<<<grdL, blk, 0, stream>>>(eh1[pw], H, H,
            eh2[pr], eWih1, eWhh1, ebih1, ebhh1, ec2, eh2[pw], ec2);
    }
    const float* encoded = eh2[0];   // after 128 steps, final write parity is 0

    // ---- decoder: autoregressive, feeds own h2 back as input ----
    for (int t = 0; t < S; ++t) {
        int pr = t & 1, pw = (t + 1) & 1;
        const float* inp = (t == 0) ? encoded : dh2[pr];
        lstm_step<<<grdL, blk, 0, stream>>>(inp, H, H,
            dh1[pr], dWih0, dWhh0, dbih0, dbhh0, dc1, dh1[pw], dc1);
        lstm_step<<<grdL, blk, 0, stream>>>(dh1[pw], H, H,
            dh2[pr], dWih1, dWhh1, dbih1, dbhh1, dc2, dh2[pw], dc2);
        proj_step<<<grdP, blk, 0, stream>>>(dh2[pw], Wout, bout, out, t);
    }
}

// Round 2
// 19843.907 us; speedup vs baseline: 1.5757x; 1.5757x over previous
//
#include <hip/hip_runtime.h>

static constexpr int B = 2048;
static constexpr int S = 128;
static constexpr int D = 128;
static constexpr int H = 256;

__device__ __forceinline__ float fsig(float x)  { return 1.0f / (1.0f + __expf(-x)); }
__device__ __forceinline__ float ftanh(float x) { return 1.0f - 2.0f / (__expf(2.0f * x) + 1.0f); }

// async global->LDS, 16B per lane. LDS dest is wave-uniform base + lane*16.
__device__ __forceinline__ void gl_lds16(const float* g, float* l) {
    __builtin_amdgcn_global_load_lds(
        (const __attribute__((address_space(1))) void*)g,
        (__attribute__((address_space(3))) void*)l,
        16, 0, 0);
}

// One GEMM-ish job: z[b, col] = sum_k A1[b,k] W1[col,k] + sum_k A2[b,k] W2[col,k]
// mode 0: col space = 4 gates x H, block covers j0..j0+31 per gate -> LSTM cell epilogue
// mode 1: col space = D (=128) cols of Wout -> projection epilogue into out[:, t, :]
struct Job {
    const float* A1; long lda1; int K1;
    const float* A2; int K2;            // lda2 == H; K2==0 -> single input pass
    const float* W1; const float* W2;   // row-major [cols, K]
    const float* bih; const float* bhh; // mode1: bih := bout
    const float* cprev; float* hout; float* cout;
    float* out; int t; int mode;
};

// 512 threads = 8 waves. Tile: 64 batch x 128 z-cols. Thread: 4 batch x 4 cols.
// LDS: double-buffered, XOR-swizzled (quad q of row r stored at q^(r&7)).
__global__ __launch_bounds__(512, 4)
void step_kernel(Job ja, Job jb)
{
    const Job J = (blockIdx.z == 0) ? ja : jb;
    if (J.mode == 1 && blockIdx.x != 0) return;   // proj uses only bx==0 (block-uniform)

    __shared__ float As[2][64 * 32];
    __shared__ float Ws[2][128 * 32];

    const int tid = threadIdx.x;
    const int tx = tid & 31;          // col within 32-group
    const int ty = tid >> 5;          // 0..15 batch subgroup
    const int wid = tid >> 6;         // wave 0..7
    const int j0 = blockIdx.x * 32;
    const int b0 = blockIdx.y * 64;

    const int n1 = J.K1 >> 5;
    const int n2 = J.K2 >> 5;
    const int nt = n1 + n2;

    auto stage = [&](int tile, int buf) {
        const bool p2 = tile >= n1;
        const float* Asrc = p2 ? J.A2 : J.A1;
        const long   lda  = p2 ? (long)H : J.lda1;
        const int    k0   = (p2 ? (tile - n1) : tile) << 5;
        const float* Wsrc = p2 ? J.W2 : J.W1;
        const int    ldw  = p2 ? J.K2 : J.K1;
        // A tile: 64 rows x 32 k = 512 float4, one per thread (linear LDS dest,
        // inverse-swizzled global source)
        {
            const int row = tid >> 3, q = tid & 7;
            const int qg = q ^ (row & 7);
            gl_lds16(Asrc + (size_t)(b0 + row) * lda + k0 + (qg << 2),
                     &As[buf][wid * 256]);
        }
        // W tile: 128 rows x 32 k = 1024 float4, two per thread
        #pragma unroll
        for (int p = 0; p < 2; ++p) {
            const int idx = tid + (p << 9);
            const int zr = idx >> 3, q = idx & 7;
            const int qg = q ^ (zr & 7);
            const int grow = (J.mode == 0) ? ((zr >> 5) * H + j0 + (zr & 31)) : zr;
            gl_lds16(Wsrc + (size_t)grow * ldw + k0 + (qg << 2),
                     &Ws[buf][(p << 11) + wid * 256]);
        }
    };

    float acc[4][4];
    #pragma unroll
    for (int r = 0; r < 4; ++r)
        #pragma unroll
        for (int g = 0; g < 4; ++g) acc[r][g] = 0.0f;

    stage(0, 0);
    asm volatile("s_waitcnt vmcnt(0)" ::: "memory");
    __builtin_amdgcn_s_barrier();

    for (int tile = 0; tile < nt; ++tile) {
        const int buf = tile & 1;
        if (tile + 1 < nt) stage(tile + 1, buf ^ 1);  // prefetch overlaps compute

        const int ka = 0;
        #pragma unroll
        for (int kq = 0; kq < 8; ++kq) {
            float4 a4[4], w4[4];
            const int kqa = (kq ^ (ty & 7)) << 2;   // same swizzle key for all 4 rows (16r = 0 mod 8)
            #pragma unroll
            for (int r = 0; r < 4; ++r)
                a4[r] = *(const float4*)&As[buf][(ty + (r << 4)) * 32 + kqa];
            const int kqw = (kq ^ (tx & 7)) << 2;
            #pragma unroll
            for (int g = 0; g < 4; ++g)
                w4[g] = *(const float4*)&Ws[buf][((g << 5) + tx) * 32 + kqw];
            #pragma unroll
            for (int r = 0; r < 4; ++r)
                #pragma unroll
                for (int g = 0; g < 4; ++g) {
                    acc[r][g] = fmaf(a4[r].x, w4[g].x, acc[r][g]);
                    acc[r][g] = fmaf(a4[r].y, w4[g].y, acc[r][g]);
                    acc[r][g] = fmaf(a4[r].z, w4[g].z, acc[r][g]);
                    acc[r][g] = fmaf(a4[r].w, w4[g].w, acc[r][g]);
                }
        }
        (void)ka;
        // prefetched loads have had the whole compute phase to land
        asm volatile("s_waitcnt vmcnt(0)" ::: "memory");
        __builtin_amdgcn_s_barrier();
    }

    if (J.mode == 0) {
        const int j = j0 + tx;
        const float bi_ = J.bih[j]         + J.bhh[j];
        const float bf_ = J.bih[H + j]     + J.bhh[H + j];
        const float bg_ = J.bih[2 * H + j] + J.bhh[2 * H + j];
        const float bo_ = J.bih[3 * H + j] + J.bhh[3 * H + j];
        #pragma unroll
        for (int r = 0; r < 4; ++r) {
            const size_t bi = (size_t)(b0 + ty + (r << 4)) * H + j;
            const float ig = fsig (acc[r][0] + bi_);
            const float fg = fsig (acc[r][1] + bf_);
            const float gg = ftanh(acc[r][2] + bg_);
            const float og = fsig (acc[r][3] + bo_);
            const float c  = fg * J.cprev[bi] + ig * gg;
            const float h  = og * ftanh(c);
            J.cout[bi] = c;
            J.hout[bi] = h;
        }
    } else {
        #pragma unroll
        for (int r = 0; r < 4; ++r) {
            const int b = b0 + ty + (r << 4);
            float* o = J.out + ((size_t)b * S + J.t) * D;
            #pragma unroll
            for (int g = 0; g < 4; ++g) {
                const int col = (g << 5) + tx;
                o[col] = acc[r][g] + J.bih[col];   // bih carries bout in mode 1
            }
        }
    }
}

extern "C" void kernel_launch(void* const* d_in, const int* in_sizes, int n_in,
                              void* d_out, int out_size, void* d_ws, size_t ws_size,
                              hipStream_t stream)
{
    const float* x     = (const float*)d_in[0];
    const float* eWih0 = (const float*)d_in[1];
    const float* eWhh0 = (const float*)d_in[2];
    const float* ebih0 = (const float*)d_in[3];
    const float* ebhh0 = (const float*)d_in[4];
    const float* eWih1 = (const float*)d_in[5];
    const float* eWhh1 = (const float*)d_in[6];
    const float* ebih1 = (const float*)d_in[7];
    const float* ebhh1 = (const float*)d_in[8];
    const float* dWih0 = (const float*)d_in[9];
    const float* dWhh0 = (const float*)d_in[10];
    const float* dbih0 = (const float*)d_in[11];
    const float* dbhh0 = (const float*)d_in[12];
    const float* dWih1 = (const float*)d_in[13];
    const float* dWhh1 = (const float*)d_in[14];
    const float* dbih1 = (const float*)d_in[15];
    const float* dbhh1 = (const float*)d_in[16];
    const float* Wout  = (const float*)d_in[17];
    const float* bout  = (const float*)d_in[18];
    float* out = (float*)d_out;

    float* ws = (float*)d_ws;
    const size_t BH = (size_t)B * H;
    float* eh1[2] = { ws + 0 * BH, ws + 1 * BH };
    float* ec1    =   ws + 2 * BH;
    float* eh2[2] = { ws + 3 * BH, ws + 4 * BH };
    float* ec2    =   ws + 5 * BH;
    float* dh1[2] = { ws + 6 * BH, ws + 7 * BH };
    float* dc1    =   ws + 8 * BH;
    float* dh2[2] = { ws + 9 * BH, ws + 10 * BH };
    float* dc2    =   ws + 11 * BH;

    hipMemsetAsync(d_ws, 0, 12 * BH * sizeof(float), stream);

    dim3 blk(512);
    dim3 g1(8, 32, 1);
    dim3 g2(8, 32, 2);
    dim3 gp(1, 32, 1);

    auto LJ = [&](const float* A1, long lda1, int K1, const float* A2, int K2,
                  const float* W1, const float* W2,
                  const float* bih, const float* bhh,
                  const float* cprev, float* hout, float* cout) {
        Job j{};
        j.A1 = A1; j.lda1 = lda1; j.K1 = K1; j.A2 = A2; j.K2 = K2;
        j.W1 = W1; j.W2 = W2; j.bih = bih; j.bhh = bhh;
        j.cprev = cprev; j.hout = hout; j.cout = cout;
        j.out = nullptr; j.t = 0; j.mode = 0;
        return j;
    };
    auto PJ = [&](const float* h2, int t) {
        Job j{};
        j.A1 = h2; j.lda1 = H; j.K1 = H; j.A2 = nullptr; j.K2 = 0;
        j.W1 = Wout; j.W2 = nullptr; j.bih = bout; j.bhh = nullptr;
        j.cprev = nullptr; j.hout = nullptr; j.cout = nullptr;
        j.out = out; j.t = t; j.mode = 1;
        return j;
    };

    // ---- encoder: software-pipelined L0(t) || L1(t-1) ----
    {
        Job a = LJ(x, (long)S * D, D, eh1[0], H,
                   eWih0, eWhh0, ebih0, ebhh0, ec1, eh1[1], ec1);
        step_kernel<<<g1, blk, 0, stream>>>(a, a);
    }
    for (int t = 1; t < S; ++t) {
        Job a = LJ(x + (size_t)t * D, (long)S * D, D, eh1[t & 1], H,
                   eWih0, eWhh0, ebih0, ebhh0, ec1, eh1[(t + 1) & 1], ec1);
        Job b = LJ(eh1[t & 1], H, H, eh2[(t - 1) & 1], H,
                   eWih1, eWhh1, ebih1, ebhh1, ec2, eh2[t & 1], ec2);
        step_kernel<<<g2, blk, 0, stream>>>(a, b);
    }
    {
        Job b = LJ(eh1[0], H, H, eh2[1], H,
                   eWih1, eWhh1, ebih1, ebhh1, ec2, eh2[0], ec2);
        step_kernel<<<g1, blk, 0, stream>>>(b, b);
    }
    const float* encoded = eh2[0];

    // ---- decoder: L0(t) || proj(t-1), L1(t) serial ----
    {
        Job a = LJ(encoded, H, H, dh1[0], H,
                   dWih0, dWhh0, dbih0, dbhh0, dc1, dh1[1], dc1);
        step_kernel<<<g1, blk, 0, stream>>>(a, a);
        Job b = LJ(dh1[1], H, H, dh2[0], H,
                   dWih1, dWhh1, dbih1, dbhh1, dc2, dh2[1], dc2);
        step_kernel<<<g1, blk, 0, stream>>>(b, b);
    }
    for (int t = 1; t < S; ++t) {
        Job a = LJ(dh2[t & 1], H, H, dh1[t & 1], H,
                   dWih0, dWhh0, dbih0, dbhh0, dc1, dh1[(t + 1) & 1], dc1);
        Job p = PJ(dh2[t & 1], t - 1);
        step_kernel<<<g2, blk, 0, stream>>>(a, p);
        Job b = LJ(dh1[(t + 1) & 1], H, H, dh2[t & 1], H,
                   dWih1, dWhh1, dbih1, dbhh1, dc2, dh2[(t + 1) & 1], dc2);
        step_kernel<<<g1, blk, 0, stream>>>(b, b);
    }
    {
        Job p = PJ(dh2[0], S - 1);
        step_kernel<<<gp, blk, 0, stream>>>(p, p);
    }
}

// Round 3
// 7017.611 us; speedup vs baseline: 4.4557x; 2.8277x over previous
//
#include <hip/hip_runtime.h>

typedef short bf16x8 __attribute__((ext_vector_type(8)));
typedef float f32x4 __attribute__((ext_vector_type(4)));
typedef unsigned short u16;
typedef unsigned int u32;

static constexpr int B = 2048, S = 128, D = 128, H = 256;

__device__ __forceinline__ u16 f2bf(float x) {
    u32 u = __float_as_uint(x);
    return (u16)((u + 0x7fffu + ((u >> 16) & 1u)) >> 16);
}
__device__ __forceinline__ float bf2f(u16 h) { return __uint_as_float(((u32)h) << 16); }
__device__ __forceinline__ float fsig(float x)  { return 1.0f / (1.0f + __expf(-x)); }
__device__ __forceinline__ float ftanh(float x) { return 1.0f - 2.0f / (__expf(2.0f * x) + 1.0f); }

__device__ __forceinline__ void gl_lds16(const void* g, void* l) {
    __builtin_amdgcn_global_load_lds(
        (const __attribute__((address_space(1))) void*)g,
        (__attribute__((address_space(3))) void*)l, 16, 0, 0);
}

// fp32 -> bf16 plane conversion (weights), once per call
__global__ __launch_bounds__(256)
void cvtk(const float* __restrict__ s, u16* __restrict__ d, int n) {
    int i = (blockIdx.x * 256 + threadIdx.x) * 4;
    if (i + 3 < n) {
        float4 v = *(const float4*)(s + i);
        d[i]     = f2bf(v.x);
        d[i + 1] = f2bf(v.y);
        d[i + 2] = f2bf(v.z);
        d[i + 3] = f2bf(v.w);
    }
}

// z[b,n] = sum_k A1[b,k] W1[n,k] + sum_k A2[b,k] W2[n,k]
// A given as bf16 hi/lo planes (exact fp32 via 2 MFMAs) or fp32 (converted on the fly).
// mode 0: n-space = 4 gates x H; block covers 4 gates x 16 j  -> LSTM cell epilogue
// mode 1: n-space = D cols of Wout (jg<2)                     -> projection epilogue
struct Job {
    const u16 *a1h, *a1l;       // bf16 planes for input part (or null)
    const float *a1f;           // fp32 input (enc L0 x); used when non-null
    long lda1; int K1;
    const u16 *a2h, *a2l; int K2;   // hprev planes, stride H
    const u16 *W1, *W2;             // bf16 [1024][K1] / [1024][K2]
    const float *bih, *bhh, *cprev;
    float *cout; u16 *hh, *hl;      // h output planes
    float *out; int t; int mode;
};

// 512 threads = 8 waves. Block tile: 128 batch x 64 n. Wave w: rows w*16..w*16+15, all 64 n.
// Wave n-tiles = 4 gates at the same 16-j range -> lane holds all 4 gates for its rows.
__global__ __launch_bounds__(512, 4)
void step_mfma(Job ja, Job jb)
{
    const Job J = (blockIdx.z == 0) ? ja : jb;
    const int jg = blockIdx.x;
    if (J.mode == 1 && jg >= 2) return;
    const int b0 = blockIdx.y * 128;

    // LDS: per buf: A rows 128 x 32k (hi,lo), W rows 64 x 32k; 16B slots swizzled
    __shared__ u16 Ah[2][128 * 32], Al[2][128 * 32], Wt[2][64 * 32];

    const int tid = threadIdx.x;
    const int w = tid >> 6, l = tid & 63;
    const int lr = l & 15, lc = l >> 4;

    const int n1 = J.K1 >> 5, n2 = J.K2 >> 5, nt = n1 + n2;

    auto stage = [&](int tile, int buf) {
        const bool p2 = tile >= n1;
        const int k0 = (p2 ? tile - n1 : tile) << 5;
        // W tile: waves 0..3, 64 rows x 4 slots
        if (w < 4) {
            const int row = tid >> 2;          // 0..63
            const int slot = tid & 3;
            const int gq = slot ^ ((row ^ (row >> 2)) & 3);
            int grow;
            if (J.mode == 0) grow = (row >> 4) * H + jg * 16 + (row & 15);
            else             grow = jg * 64 + row;
            const u16* Wsrc = p2 ? J.W2 : J.W1;
            const int ldw = p2 ? J.K2 : J.K1;
            gl_lds16(Wsrc + (size_t)grow * ldw + k0 + gq * 8, &Wt[buf][w * 512]);
        }
        // A tile: all 8 waves, 128 rows x 4 slots
        const int row = tid >> 2;              // 0..127
        const int slot = tid & 3;
        const int gq = slot ^ ((row ^ (row >> 2)) & 3);
        if (!p2 && J.a1f) {
            // fp32 source: reg-stage + convert to hi/lo, swizzled ds_write
            const float* src = J.a1f + (size_t)(b0 + row) * J.lda1 + k0 + gq * 8;
            f32x4 v0 = *(const f32x4*)src;
            f32x4 v1 = *(const f32x4*)(src + 4);
            float vv[8];
            *(f32x4*)vv = v0; *(f32x4*)(vv + 4) = v1;
            u16 h8[8], l8[8];
            #pragma unroll
            for (int i = 0; i < 8; ++i) {
                u16 hb = f2bf(vv[i]);
                h8[i] = hb;
                l8[i] = f2bf(vv[i] - bf2f(hb));
            }
            *(bf16x8*)&Ah[buf][row * 32 + slot * 8] = *(bf16x8*)h8;
            *(bf16x8*)&Al[buf][row * 32 + slot * 8] = *(bf16x8*)l8;
        } else {
            const u16* sh = p2 ? J.a2h : J.a1h;
            const u16* sl = p2 ? J.a2l : J.a1l;
            const long lda = p2 ? (long)H : J.lda1;
            const size_t off = (size_t)(b0 + row) * lda + k0 + gq * 8;
            gl_lds16(sh + off, &Ah[buf][w * 512]);
            gl_lds16(sl + off, &Al[buf][w * 512]);
        }
    };

    // precomputed swizzled read offsets (u16 elems)
    const int arow = w * 16 + lr;
    const int aoff = arow * 32 + ((lc ^ ((arow ^ (arow >> 2)) & 3)) * 8);
    int boff[4];
    #pragma unroll
    for (int g = 0; g < 4; ++g) {
        const int nr = g * 16 + lr;
        boff[g] = nr * 32 + ((lc ^ ((nr ^ (nr >> 2)) & 3)) * 8);
    }

    f32x4 acc[4] = {};

    stage(0, 0);
    asm volatile("s_waitcnt vmcnt(0) lgkmcnt(0)" ::: "memory");
    __builtin_amdgcn_s_barrier();

    for (int t = 0; t < nt; ++t) {
        const int buf = t & 1;
        if (t + 1 < nt) stage(t + 1, buf ^ 1);
        bf16x8 ah = *(const bf16x8*)&Ah[buf][aoff];
        bf16x8 al = *(const bf16x8*)&Al[buf][aoff];
        #pragma unroll
        for (int g = 0; g < 4; ++g) {
            bf16x8 bg = *(const bf16x8*)&Wt[buf][boff[g]];
            acc[g] = __builtin_amdgcn_mfma_f32_16x16x32_bf16(ah, bg, acc[g], 0, 0, 0);
            acc[g] = __builtin_amdgcn_mfma_f32_16x16x32_bf16(al, bg, acc[g], 0, 0, 0);
        }
        asm volatile("s_waitcnt vmcnt(0) lgkmcnt(0)" ::: "memory");
        __builtin_amdgcn_s_barrier();
    }

    if (J.mode == 0) {
        const int j = jg * 16 + lr;
        const float bi_ = J.bih[j]         + J.bhh[j];
        const float bf_ = J.bih[H + j]     + J.bhh[H + j];
        const float bg_ = J.bih[2 * H + j] + J.bhh[2 * H + j];
        const float bo_ = J.bih[3 * H + j] + J.bhh[3 * H + j];
        #pragma unroll
        for (int r = 0; r < 4; ++r) {
            const int m = b0 + w * 16 + lc * 4 + r;
            const size_t idx = (size_t)m * H + j;
            const float ig = fsig (acc[0][r] + bi_);
            const float fg = fsig (acc[1][r] + bf_);
            const float gg = ftanh(acc[2][r] + bg_);
            const float og = fsig (acc[3][r] + bo_);
            const float c  = fg * J.cprev[idx] + ig * gg;
            const float h  = og * ftanh(c);
            J.cout[idx] = c;
            const u16 hb = f2bf(h);
            J.hh[idx] = hb;
            J.hl[idx] = f2bf(h - bf2f(hb));
        }
    } else {
        #pragma unroll
        for (int g = 0; g < 4; ++g) {
            const int col = jg * 64 + g * 16 + lr;
            const float bo = J.bih[col];    // bih carries bout
            #pragma unroll
            for (int r = 0; r < 4; ++r) {
                const int m = b0 + w * 16 + lc * 4 + r;
                J.out[((size_t)m * S + J.t) * D + col] = acc[g][r] + bo;
            }
        }
    }
}

extern "C" void kernel_launch(void* const* d_in, const int* in_sizes, int n_in,
                              void* d_out, int out_size, void* d_ws, size_t ws_size,
                              hipStream_t stream)
{
    const float* x     = (const float*)d_in[0];
    const float* eWih0 = (const float*)d_in[1];
    const float* eWhh0 = (const float*)d_in[2];
    const float* ebih0 = (const float*)d_in[3];
    const float* ebhh0 = (const float*)d_in[4];
    const float* eWih1 = (const float*)d_in[5];
    const float* eWhh1 = (const float*)d_in[6];
    const float* ebih1 = (const float*)d_in[7];
    const float* ebhh1 = (const float*)d_in[8];
    const float* dWih0 = (const float*)d_in[9];
    const float* dWhh0 = (const float*)d_in[10];
    const float* dbih0 = (const float*)d_in[11];
    const float* dbhh0 = (const float*)d_in[12];
    const float* dWih1 = (const float*)d_in[13];
    const float* dWhh1 = (const float*)d_in[14];
    const float* dbih1 = (const float*)d_in[15];
    const float* dbhh1 = (const float*)d_in[16];
    const float* Wout  = (const float*)d_in[17];
    const float* bout  = (const float*)d_in[18];
    float* out = (float*)d_out;

    // ---- workspace layout ----
    u16* wc = (u16*)d_ws;
    const int szW[9] = {4*H*D, 4*H*H, 4*H*H, 4*H*H, 4*H*H, 4*H*H, 4*H*H, 4*H*H, D*H};
    const float* srcW[9] = {eWih0, eWhh0, eWih1, eWhh1, dWih0, dWhh0, dWih1, dWhh1, Wout};
    u16* dstW[9]; size_t woff = 0;
    for (int i = 0; i < 9; ++i) { dstW[i] = wc + woff; woff += (size_t)szW[i]; }
    // h planes: 16 planes of B*H bf16
    const size_t PH = (size_t)B * H;
    u16* pl = wc + woff;
    u16 *eh1h[2], *eh1l[2], *eh2h[2], *eh2l[2], *dh1h[2], *dh1l[2], *dh2h[2], *dh2l[2];
    {
        u16** tbl[16] = {&eh1h[0], &eh1l[0], &eh1h[1], &eh1l[1],
                         &eh2h[0], &eh2l[0], &eh2h[1], &eh2l[1],
                         &dh1h[0], &dh1l[0], &dh1h[1], &dh1l[1],
                         &dh2h[0], &dh2l[0], &dh2h[1], &dh2l[1]};
        for (int i = 0; i < 16; ++i) *tbl[i] = pl + (size_t)i * PH;
    }
    float* cbase = (float*)(pl + 16 * PH);
    float* c1 = cbase;            // enc L0 c, reused as dec L0 c
    float* c2 = cbase + PH;       // enc L1 c, reused as dec L1 c

    // ---- convert weights to bf16 (every call; deterministic) ----
    for (int i = 0; i < 9; ++i)
        cvtk<<<dim3(szW[i] / 1024), dim3(256), 0, stream>>>(srcW[i], dstW[i], szW[i]);
    // zero h planes + c
    hipMemsetAsync(pl, 0, 16 * PH * sizeof(u16) + 2 * PH * sizeof(float), stream);

    dim3 blk(512);
    dim3 g1(16, 16, 1), g2(16, 16, 2), gp(2, 16, 1);

    auto LJ = [&](const u16* a1h, const u16* a1l, const float* a1f, long lda1, int K1,
                  const u16* a2h, const u16* a2l, int K2,
                  const u16* W1, const u16* W2,
                  const float* bih, const float* bhh,
                  const float* cprev, float* cout, u16* hh, u16* hl) {
        Job j{};
        j.a1h = a1h; j.a1l = a1l; j.a1f = a1f; j.lda1 = lda1; j.K1 = K1;
        j.a2h = a2h; j.a2l = a2l; j.K2 = K2;
        j.W1 = W1; j.W2 = W2; j.bih = bih; j.bhh = bhh;
        j.cprev = cprev; j.cout = cout; j.hh = hh; j.hl = hl;
        j.out = nullptr; j.t = 0; j.mode = 0;
        return j;
    };
    auto PJ = [&](const u16* ah, const u16* al, int t) {
        Job j{};
        j.a1h = ah; j.a1l = al; j.a1f = nullptr; j.lda1 = H; j.K1 = H; j.K2 = 0;
        j.W1 = dstW[8]; j.W2 = nullptr; j.bih = bout; j.bhh = nullptr;
        j.cprev = nullptr; j.cout = nullptr; j.hh = nullptr; j.hl = nullptr;
        j.out = out; j.t = t; j.mode = 1;
        return j;
    };

    // ---- encoder: pipelined L0(t) || L1(t-1) ----
    {
        Job a = LJ(nullptr, nullptr, x, (long)S * D, D, eh1h[0], eh1l[0], H,
                   dstW[0], dstW[1], ebih0, ebhh0, c1, c1, eh1h[1], eh1l[1]);
        step_mfma<<<g1, blk, 0, stream>>>(a, a);
    }
    for (int t = 1; t < S; ++t) {
        Job a = LJ(nullptr, nullptr, x + (size_t)t * D, (long)S * D, D,
                   eh1h[t & 1], eh1l[t & 1], H,
                   dstW[0], dstW[1], ebih0, ebhh0, c1, c1, eh1h[(t + 1) & 1], eh1l[(t + 1) & 1]);
        Job b = LJ(eh1h[t & 1], eh1l[t & 1], nullptr, H, H,
                   eh2h[(t - 1) & 1], eh2l[(t - 1) & 1], H,
                   dstW[2], dstW[3], ebih1, ebhh1, c2, c2, eh2h[t & 1], eh2l[t & 1]);
        step_mfma<<<g2, blk, 0, stream>>>(a, b);
    }
    {
        Job b = LJ(eh1h[0], eh1l[0], nullptr, H, H, eh2h[1], eh2l[1], H,
                   dstW[2], dstW[3], ebih1, ebhh1, c2, c2, eh2h[0], eh2l[0]);
        step_mfma<<<g1, blk, 0, stream>>>(b, b);
    }
    // encoded = eh2[0] planes

    // re-zero c for decoder reuse
    hipMemsetAsync(cbase, 0, 2 * PH * sizeof(float), stream);

    // ---- decoder: L0(t) || proj(t-1); L1(t) serial ----
    {
        Job a = LJ(eh2h[0], eh2l[0], nullptr, H, H, dh1h[0], dh1l[0], H,
                   dstW[4], dstW[5], dbih0, dbhh0, c1, c1, dh1h[1], dh1l[1]);
        step_mfma<<<g1, blk, 0, stream>>>(a, a);
        Job b = LJ(dh1h[1], dh1l[1], nullptr, H, H, dh2h[0], dh2l[0], H,
                   dstW[6], dstW[7], dbih1, dbhh1, c2, c2, dh2h[1], dh2l[1]);
        step_mfma<<<g1, blk, 0, stream>>>(b, b);
    }
    for (int t = 1; t < S; ++t) {
        Job a = LJ(dh2h[t & 1], dh2l[t & 1], nullptr, H, H, dh1h[t & 1], dh1l[t & 1], H,
                   dstW[4], dstW[5], dbih0, dbhh0, c1, c1, dh1h[(t + 1) & 1], dh1l[(t + 1) & 1]);
        Job p = PJ(dh2h[t & 1], dh2l[t & 1], t - 1);
        step_mfma<<<g2, blk, 0, stream>>>(a, p);
        Job b = LJ(dh1h[(t + 1) & 1], dh1l[(t + 1) & 1], nullptr, H, H,
                   dh2h[t & 1], dh2l[t & 1], H,
                   dstW[6], dstW[7], dbih1, dbhh1, c2, c2, dh2h[(t + 1) & 1], dh2l[(t + 1) & 1]);
        step_mfma<<<g1, blk, 0, stream>>>(b, b);
    }
    {
        Job p = PJ(dh2h[0], dh2l[0], S - 1);
        step_mfma<<<gp, blk, 0, stream>>>(p, p);
    }
}